// Round 3
// baseline (424.477 us; speedup 1.0000x reference)
//
#include <hip/hip_runtime.h>

#define NN 50000
#define NE 800000
#define D_NODE 64
#define D_ATTR 16
#define D_T 16
#define D_MSG 96      // 64 + 16 + 16
#define D_OUT 128

// ---------------- ws layout (fast path) ----------------
#define CNT_OFF  0
#define OFF_OFF  (NN * 4)
#define CUR_OFF  (2 * NN * 4)
#define PERM_OFF 600000
#define AGG_OFF  7000000
#define WS_NEEDED (AGG_OFF + NN * D_MSG * 4)

// ---------------------------------------------------------------------------
// Step 1: per-row histogram
// ---------------------------------------------------------------------------
__global__ __launch_bounds__(256) void hist_kernel(
    const int* __restrict__ row, int* __restrict__ cnt)
{
    int e = blockIdx.x * blockDim.x + threadIdx.x;
    if (e < NE) atomicAdd(&cnt[row[e]], 1);
}

// ---------------------------------------------------------------------------
// Step 2: exclusive prefix scan of cnt -> off (and cur copy). Single block.
// ---------------------------------------------------------------------------
__global__ __launch_bounds__(1024) void scan_kernel(
    const int* __restrict__ cnt, int* __restrict__ off, int* __restrict__ cur)
{
    __shared__ int part[1024];
    const int t = threadIdx.x;
    const int per = (NN + 1023) / 1024;   // 49
    const int base = t * per;

    int s = 0;
    for (int i = 0; i < per; ++i) {
        int idx = base + i;
        if (idx < NN) s += cnt[idx];
    }
    part[t] = s;
    __syncthreads();
    for (int d = 1; d < 1024; d <<= 1) {
        int v = (t >= d) ? part[t - d] : 0;
        __syncthreads();
        part[t] += v;
        __syncthreads();
    }
    int run = (t == 0) ? 0 : part[t - 1];
    for (int i = 0; i < per; ++i) {
        int idx = base + i;
        if (idx < NN) {
            off[idx] = run;
            cur[idx] = run;
            run += cnt[idx];
        }
    }
}

// ---------------------------------------------------------------------------
// Step 3: bucket edges into CSR slots; store (e, col[e]).
// ---------------------------------------------------------------------------
__global__ __launch_bounds__(256) void bucket_kernel(
    const int* __restrict__ row, const int* __restrict__ col,
    int* __restrict__ cur, int2* __restrict__ perm)
{
    int e = blockIdx.x * blockDim.x + threadIdx.x;
    if (e >= NE) return;
    int pos = atomicAdd(&cur[row[e]], 1);
    perm[pos] = make_int2(e, col[e]);
}

// ---------------------------------------------------------------------------
// Step 4: gather-aggregate. One wave64 per node; edge loop unrolled x2
// (independent acc sets -> 2x outstanding loads).
// ---------------------------------------------------------------------------
__global__ __launch_bounds__(256) void gather_kernel(
    const float* __restrict__ x,    // NN x 64
    const float* __restrict__ ea,   // NE x 16
    const float* __restrict__ et,   // NE x 16
    const int*  __restrict__ off,
    const int*  __restrict__ cnt,
    const int2* __restrict__ perm,
    float* __restrict__ agg)        // NN x 96
{
    const int node = blockIdx.x * 4 + (threadIdx.x >> 6);
    const int lane = threadIdx.x & 63;
    if (node >= NN) return;

    const int beg = off[node];
    const int n   = cnt[node];

    const float* eb = (lane < 16) ? (ea + lane) : (et + (lane - 16));

    float acc0 = 0.f, acc1 = 0.f, acc0b = 0.f, acc1b = 0.f;
    int j = 0;
    for (; j + 2 <= n; j += 2) {
        int2 pa = perm[beg + j];
        int2 pb = perm[beg + j + 1];
        acc0  += x[(size_t)pa.y * D_NODE + lane];
        acc0b += x[(size_t)pb.y * D_NODE + lane];
        if (lane < 32) {
            acc1  += eb[(size_t)pa.x * 16];
            acc1b += eb[(size_t)pb.x * 16];
        }
    }
    if (j < n) {
        int2 pa = perm[beg + j];
        acc0 += x[(size_t)pa.y * D_NODE + lane];
        if (lane < 32) acc1 += eb[(size_t)pa.x * 16];
    }
    acc0 += acc0b;
    acc1 += acc1b;

    float* dst = agg + (size_t)node * D_MSG;
    dst[lane] = acc0;
    if (lane < 32) dst[D_NODE + lane] = acc1;
}

// ---------------------------------------------------------------------------
// Fallback phase 1 (atomic scatter), used only if ws is too small.
// ---------------------------------------------------------------------------
__global__ __launch_bounds__(256) void scatter_kernel(
    const float4* __restrict__ x4,
    const int*    __restrict__ row,
    const int*    __restrict__ col,
    const float4* __restrict__ ea4,
    const float4* __restrict__ et4,
    float*        __restrict__ agg)
{
    int t = blockIdx.x * blockDim.x + threadIdx.x;
    const int total = NE * 24;
    if (t >= total) return;
    int e = t / 24;
    int c = t - e * 24;

    float4 v;
    if (c < 16) {
        int s = col[e];
        v = x4[(size_t)s * 16 + c];
    } else if (c < 20) {
        v = ea4[(size_t)e * 4 + (c - 16)];
    } else {
        v = et4[(size_t)e * 4 + (c - 20)];
    }

    float* dst = agg + (size_t)row[e] * D_MSG + c * 4;
    unsafeAtomicAdd(dst + 0, v.x);
    unsafeAtomicAdd(dst + 1, v.y);
    unsafeAtomicAdd(dst + 2, v.z);
    unsafeAtomicAdd(dst + 3, v.w);
}

// ---------------------------------------------------------------------------
// Phase 2: out[n,o] = 0.5*(agg[n,:]@Wm[:,o]) + (x[n,:]@Wr[:,o]) + (0.5*bm+br)
// 512 threads = 4 groups x 128 (thread = output col o). Weights staged in LDS
// TRANSPOSED-IN-CHUNKS: sWm4[k4][o] = float4(Wm[4k4..4k4+3][o]) so each k4
// step is ONE ds_read_b128 feeding 8 nodes x 4 k = 32 FMAs (compute-bound).
// 8-node register tile; grid covers all nodes (no loop) -> 2 blocks/CU.
// ---------------------------------------------------------------------------
__global__ __launch_bounds__(512) void dense_kernel(
    const float* __restrict__ agg,
    const float* __restrict__ x,
    const float* __restrict__ Wm,
    const float* __restrict__ bm,
    const float* __restrict__ Wr,
    const float* __restrict__ br,
    float*       __restrict__ out)
{
    __shared__ float4 sWm4[(D_MSG / 4) * D_OUT];   // 24*128*16B = 49152B
    __shared__ float4 sWr4[(D_NODE / 4) * D_OUT];  // 16*128*16B = 32768B

    for (int idx = threadIdx.x; idx < (D_MSG / 4) * D_OUT; idx += 512) {
        int k4 = idx >> 7, o = idx & 127;
        sWm4[idx] = make_float4(Wm[(4 * k4 + 0) * D_OUT + o],
                                Wm[(4 * k4 + 1) * D_OUT + o],
                                Wm[(4 * k4 + 2) * D_OUT + o],
                                Wm[(4 * k4 + 3) * D_OUT + o]);
    }
    for (int idx = threadIdx.x; idx < (D_NODE / 4) * D_OUT; idx += 512) {
        int k4 = idx >> 7, o = idx & 127;
        sWr4[idx] = make_float4(Wr[(4 * k4 + 0) * D_OUT + o],
                                Wr[(4 * k4 + 1) * D_OUT + o],
                                Wr[(4 * k4 + 2) * D_OUT + o],
                                Wr[(4 * k4 + 3) * D_OUT + o]);
    }
    __syncthreads();

    const int o = threadIdx.x & 127;
    const int g = threadIdx.x >> 7;
    const int n0 = (blockIdx.x * 4 + g) * 8;       // 8-node tile; NN % 8 == 0
    if (n0 >= NN) return;                          // no barriers after this

    const float bias = 0.5f * bm[o] + br[o];

    float accm[8] = {0.f, 0.f, 0.f, 0.f, 0.f, 0.f, 0.f, 0.f};
    float accr[8] = {0.f, 0.f, 0.f, 0.f, 0.f, 0.f, 0.f, 0.f};

    const float* aggb = agg + (size_t)n0 * D_MSG;
#pragma unroll 2
    for (int k4 = 0; k4 < D_MSG / 4; ++k4) {
        float4 w = sWm4[k4 * D_OUT + o];
#pragma unroll
        for (int j = 0; j < 8; ++j) {
            float4 a = *(const float4*)(aggb + j * D_MSG + k4 * 4);
            accm[j] = fmaf(a.w, w.w, fmaf(a.z, w.z,
                      fmaf(a.y, w.y, fmaf(a.x, w.x, accm[j]))));
        }
    }

    const float* xb = x + (size_t)n0 * D_NODE;
#pragma unroll 2
    for (int k4 = 0; k4 < D_NODE / 4; ++k4) {
        float4 w = sWr4[k4 * D_OUT + o];
#pragma unroll
        for (int j = 0; j < 8; ++j) {
            float4 a = *(const float4*)(xb + j * D_NODE + k4 * 4);
            accr[j] = fmaf(a.w, w.w, fmaf(a.z, w.z,
                      fmaf(a.y, w.y, fmaf(a.x, w.x, accr[j]))));
        }
    }

#pragma unroll
    for (int j = 0; j < 8; ++j)
        out[(size_t)(n0 + j) * D_OUT + o] = 0.5f * accm[j] + accr[j] + bias;
}

extern "C" void kernel_launch(void* const* d_in, const int* in_sizes, int n_in,
                              void* d_out, int out_size, void* d_ws, size_t ws_size,
                              hipStream_t stream) {
    const float* x  = (const float*)d_in[0];
    const int*   ei = (const int*)d_in[1];   // row = ei[0:NE), col = ei[NE:2NE)
    const float* ea = (const float*)d_in[2];
    const float* et = (const float*)d_in[3];
    const float* Wm = (const float*)d_in[4];
    const float* bm = (const float*)d_in[5];
    const float* Wr = (const float*)d_in[6];
    const float* br = (const float*)d_in[7];
    float* out = (float*)d_out;
    const int* row = ei;
    const int* col = ei + NE;

    char* ws = (char*)d_ws;
    const int dense_grid = (NN / 8 + 3) / 4;   // 1563

    if (ws_size >= (size_t)WS_NEEDED) {
        int*  cnt  = (int*)(ws + CNT_OFF);
        int*  off  = (int*)(ws + OFF_OFF);
        int*  cur  = (int*)(ws + CUR_OFF);
        int2* perm = (int2*)(ws + PERM_OFF);
        float* agg = (float*)(ws + AGG_OFF);

        hipMemsetAsync(cnt, 0, NN * sizeof(int), stream);
        hist_kernel<<<(NE + 255) / 256, 256, 0, stream>>>(row, cnt);
        scan_kernel<<<1, 1024, 0, stream>>>(cnt, off, cur);
        bucket_kernel<<<(NE + 255) / 256, 256, 0, stream>>>(row, col, cur, perm);
        gather_kernel<<<(NN + 3) / 4, 256, 0, stream>>>(x, ea, et, off, cnt, perm, agg);
        dense_kernel<<<dense_grid, 512, 0, stream>>>(agg, x, Wm, bm, Wr, br, out);
    } else {
        float* agg = (float*)d_ws;
        hipMemsetAsync(agg, 0, (size_t)NN * D_MSG * sizeof(float), stream);
        const int total = NE * 24;
        scatter_kernel<<<(total + 255) / 256, 256, 0, stream>>>(
            (const float4*)x, row, col, (const float4*)ea, (const float4*)et, agg);
        dense_kernel<<<dense_grid, 512, 0, stream>>>(agg, x, Wm, bm, Wr, br, out);
    }
}

// Round 4
// 296.651 us; speedup vs baseline: 1.4309x; 1.4309x over previous
//
#include <hip/hip_runtime.h>
#include <hip/hip_bf16.h>

#define NN 50000
#define NE 800000
#define D_NODE 64
#define D_MSG 96      // 64 + 16 + 16
#define D_K 160       // 96 (0.5*agg) + 64 (x)
#define D_OUT 128
#define KP 168        // LDS-padded K stride for Bt

typedef __attribute__((ext_vector_type(8))) short bf16x8;
typedef __attribute__((ext_vector_type(4))) float f32x4;

// ---------------- ws layout ----------------
// cnt : NN int        @ 0
// off : NN int        @ 200000
// cur : NN int        @ 400000
// perm: NE int2       @ 600000   (8B aligned)
// A   : NN x 160 bf16 @ 7000064  (16B aligned)
#define CNT_OFF  0
#define OFF_OFF  200000
#define CUR_OFF  400000
#define PERM_OFF 600000
#define A_OFF    7000064
#define WS_NEEDED (A_OFF + (size_t)NN * D_K * 2)

__device__ __forceinline__ unsigned short f2bf(float f) {
    __hip_bfloat16 h = __float2bfloat16(f);   // RNE
    union { __hip_bfloat16 h; unsigned short u; } c; c.h = h;
    return c.u;
}

// ---------------------------------------------------------------------------
// Step 1: per-row histogram
// ---------------------------------------------------------------------------
__global__ __launch_bounds__(256) void hist_kernel(
    const int* __restrict__ row, int* __restrict__ cnt)
{
    int e = blockIdx.x * blockDim.x + threadIdx.x;
    if (e < NE) atomicAdd(&cnt[row[e]], 1);
}

// ---------------------------------------------------------------------------
// Step 2: exclusive prefix scan of cnt -> off (and cur copy). Single block.
// ---------------------------------------------------------------------------
__global__ __launch_bounds__(1024) void scan_kernel(
    const int* __restrict__ cnt, int* __restrict__ off, int* __restrict__ cur)
{
    __shared__ int part[1024];
    const int t = threadIdx.x;
    const int per = (NN + 1023) / 1024;   // 49
    const int base = t * per;

    int s = 0;
    for (int i = 0; i < per; ++i) {
        int idx = base + i;
        if (idx < NN) s += cnt[idx];
    }
    part[t] = s;
    __syncthreads();
    for (int d = 1; d < 1024; d <<= 1) {
        int v = (t >= d) ? part[t - d] : 0;
        __syncthreads();
        part[t] += v;
        __syncthreads();
    }
    int run = (t == 0) ? 0 : part[t - 1];
    for (int i = 0; i < per; ++i) {
        int idx = base + i;
        if (idx < NN) {
            off[idx] = run;
            cur[idx] = run;
            run += cnt[idx];
        }
    }
}

// ---------------------------------------------------------------------------
// Step 3: bucket edges into CSR slots; store (e, col[e]).
// ---------------------------------------------------------------------------
__global__ __launch_bounds__(256) void bucket_kernel(
    const int* __restrict__ row, const int* __restrict__ col,
    int* __restrict__ cur, int2* __restrict__ perm)
{
    int e = blockIdx.x * blockDim.x + threadIdx.x;
    if (e >= NE) return;
    int pos = atomicAdd(&cur[row[e]], 1);
    perm[pos] = make_int2(e, col[e]);
}

// ---------------------------------------------------------------------------
// Step 4: gather-aggregate. One wave64 per node; edge loop unrolled x4.
// Writes A row directly as bf16: cols 0..95 = 0.5*(sum msg), cols 96..159 = x[node].
// ---------------------------------------------------------------------------
__global__ __launch_bounds__(256) void gather_kernel(
    const float* __restrict__ x,    // NN x 64
    const float* __restrict__ ea,   // NE x 16
    const float* __restrict__ et,   // NE x 16
    const int*  __restrict__ off,
    const int*  __restrict__ cnt,
    const int2* __restrict__ perm,
    unsigned short* __restrict__ A) // NN x 160 bf16
{
    const int node = blockIdx.x * 4 + (threadIdx.x >> 6);
    const int lane = threadIdx.x & 63;
    if (node >= NN) return;

    const int beg = off[node];
    const int n   = cnt[node];

    const float* eb = (lane < 16) ? (ea + lane) : (et + (lane - 16));

    float a0 = 0.f, a1 = 0.f, a2 = 0.f, a3 = 0.f;
    float b0 = 0.f, b1 = 0.f, b2 = 0.f, b3 = 0.f;
    int j = 0;
    for (; j + 4 <= n; j += 4) {
        int2 p0 = perm[beg + j];
        int2 p1 = perm[beg + j + 1];
        int2 p2 = perm[beg + j + 2];
        int2 p3 = perm[beg + j + 3];
        a0 += x[(size_t)p0.y * D_NODE + lane];
        a1 += x[(size_t)p1.y * D_NODE + lane];
        a2 += x[(size_t)p2.y * D_NODE + lane];
        a3 += x[(size_t)p3.y * D_NODE + lane];
        if (lane < 32) {
            b0 += eb[(size_t)p0.x * 16];
            b1 += eb[(size_t)p1.x * 16];
            b2 += eb[(size_t)p2.x * 16];
            b3 += eb[(size_t)p3.x * 16];
        }
    }
    for (; j < n; ++j) {
        int2 p = perm[beg + j];
        a0 += x[(size_t)p.y * D_NODE + lane];
        if (lane < 32) b0 += eb[(size_t)p.x * 16];
    }
    float accx = (a0 + a1) + (a2 + a3);
    float acce = (b0 + b1) + (b2 + b3);

    unsigned short* dst = A + (size_t)node * D_K;
    dst[lane] = f2bf(0.5f * accx);                       // cols 0..63
    if (lane < 32) dst[D_NODE + lane] = f2bf(0.5f * acce); // cols 64..95
    dst[D_MSG + lane] = f2bf(x[(size_t)node * D_NODE + lane]); // cols 96..159
}

// ---------------------------------------------------------------------------
// Step 5: MFMA GEMM  out[50000,128] = A[50000,160] @ B[160,128] + bias
// B = [Wm ; Wr] (0.5 already folded into A cols 0..95). bias = 0.5*bm+br.
// Block 256 = 4 waves (2M x 2N). Block tile 64M x 128N, K=160 (5 steps of 32).
// Bt staged in LDS bf16 (transposed, stride KP), all 20 B-frags preloaded to
// VGPRs per wave; A-frags loaded straight from global (16B/lane).
// mfma_f32_16x16x32_bf16 layouts: A row=l&15, k=(l>>4)*8+j; B col=l&15 same k;
// C col=l&15, row=(l>>4)*4+reg.
// ---------------------------------------------------------------------------
__global__ __launch_bounds__(256) void mfma_dense_kernel(
    const unsigned short* __restrict__ A,  // NN x 160 bf16
    const float* __restrict__ Wm,          // 96 x 128
    const float* __restrict__ bm,          // 128
    const float* __restrict__ Wr,          // 64 x 128
    const float* __restrict__ br,          // 128
    float*       __restrict__ out)         // NN x 128
{
    __shared__ unsigned short Bt[D_OUT * KP];   // 128*168*2 = 43008 B

    for (int i = threadIdx.x; i < D_K * D_OUT; i += 256) {
        int k = i >> 7, n = i & 127;           // coalesced read
        float v = (k < D_MSG) ? Wm[i] : Wr[i - D_MSG * D_OUT];
        Bt[n * KP + k] = f2bf(v);
    }
    __syncthreads();

    const int l   = threadIdx.x & 63;
    const int wid = threadIdx.x >> 6;
    const int wm  = wid & 1;                   // M half (32 rows)
    const int wn  = wid >> 1;                  // N half (64 cols)
    const int lr  = l & 15;
    const int lk  = (l >> 4) << 3;             // k sub-offset 0/8/16/24

    // preload B fragments: bq[nf][ks]
    bf16x8 bq[4][5];
#pragma unroll
    for (int nf = 0; nf < 4; ++nf) {
        int c = wn * 64 + nf * 16 + lr;
#pragma unroll
        for (int ks = 0; ks < 5; ++ks)
            bq[nf][ks] = *(const bf16x8*)(&Bt[c * KP + ks * 32 + lk]);
    }

    const int row0 = blockIdx.x * 64 + wm * 32;

    f32x4 acc[2][4];
#pragma unroll
    for (int mf = 0; mf < 2; ++mf)
#pragma unroll
        for (int nf = 0; nf < 4; ++nf)
            acc[mf][nf] = (f32x4){0.f, 0.f, 0.f, 0.f};

#pragma unroll
    for (int ks = 0; ks < 5; ++ks) {
#pragma unroll
        for (int mf = 0; mf < 2; ++mf) {
            int row = row0 + mf * 16 + lr;
            if (row > NN - 1) row = NN - 1;    // clamp (garbage rows never stored)
            bf16x8 af = *(const bf16x8*)(A + (size_t)row * D_K + ks * 32 + lk);
#pragma unroll
            for (int nf = 0; nf < 4; ++nf)
                acc[mf][nf] = __builtin_amdgcn_mfma_f32_16x16x32_bf16(
                    af, bq[nf][ks], acc[mf][nf], 0, 0, 0);
        }
    }

#pragma unroll
    for (int nf = 0; nf < 4; ++nf) {
        int c = wn * 64 + nf * 16 + lr;
        float bias = 0.5f * bm[c] + br[c];
#pragma unroll
        for (int mf = 0; mf < 2; ++mf) {
            int rbase = row0 + mf * 16 + ((l >> 4) << 2);
#pragma unroll
            for (int r = 0; r < 4; ++r) {
                int row = rbase + r;
                if (row < NN) out[(size_t)row * D_OUT + c] = acc[mf][nf][r] + bias;
            }
        }
    }
}

extern "C" void kernel_launch(void* const* d_in, const int* in_sizes, int n_in,
                              void* d_out, int out_size, void* d_ws, size_t ws_size,
                              hipStream_t stream) {
    const float* x  = (const float*)d_in[0];
    const int*   ei = (const int*)d_in[1];   // row = ei[0:NE), col = ei[NE:2NE)
    const float* ea = (const float*)d_in[2];
    const float* et = (const float*)d_in[3];
    const float* Wm = (const float*)d_in[4];
    const float* bm = (const float*)d_in[5];
    const float* Wr = (const float*)d_in[6];
    const float* br = (const float*)d_in[7];
    float* out = (float*)d_out;
    const int* row = ei;
    const int* col = ei + NE;

    char* ws = (char*)d_ws;
    int*  cnt  = (int*)(ws + CNT_OFF);
    int*  off  = (int*)(ws + OFF_OFF);
    int*  cur  = (int*)(ws + CUR_OFF);
    int2* perm = (int2*)(ws + PERM_OFF);
    unsigned short* A = (unsigned short*)(ws + A_OFF);

    hipMemsetAsync(cnt, 0, NN * sizeof(int), stream);
    hist_kernel  <<<(NE + 255) / 256, 256, 0, stream>>>(row, cnt);
    scan_kernel  <<<1, 1024, 0, stream>>>(cnt, off, cur);
    bucket_kernel<<<(NE + 255) / 256, 256, 0, stream>>>(row, col, cur, perm);
    gather_kernel<<<(NN + 3) / 4, 256, 0, stream>>>(x, ea, et, off, cnt, perm, A);
    mfma_dense_kernel<<<(NN + 63) / 64, 256, 0, stream>>>(A, Wm, bm, Wr, br, out);
}

// Round 6
// 183.155 us; speedup vs baseline: 2.3176x; 1.6197x over previous
//
#include <hip/hip_runtime.h>
#include <hip/hip_bf16.h>

#define NN 50000
#define NE 800000
#define D_NODE 64
#define D_MSG 96      // 64 + 16 + 16
#define D_K 160       // 96 (0.5*agg) + 64 (x)
#define D_OUT 128
#define KP 168        // LDS-padded K stride for Bt

#define SCAN_BLOCKS 49   // ceil(12500 int4 groups / 256)

typedef __attribute__((ext_vector_type(8))) short bf16x8;
typedef __attribute__((ext_vector_type(4))) float f32x4;

// ---------------- ws layout (all ranges disjoint!) ----------------
// cnt : [0,        200000)
// off : [200000,   400000)
// cur : [400000,   600000)
// perm: [600000,   7000000)   NE * 8
// A   : [7000064,  23000064)  NN * 160 * 2
// bsum: [23000064, 23000260)  49 ints  -- AFTER A; was overlapping cur (r5 crash)
#define CNT_OFF  0
#define OFF_OFF  200000
#define CUR_OFF  400000
#define PERM_OFF 600000
#define A_OFF    7000064
#define BSUM_OFF 23000064
#define WS_NEEDED (BSUM_OFF + SCAN_BLOCKS * 4)

__device__ __forceinline__ unsigned short f2bf(float f) {
    __hip_bfloat16 h = __float2bfloat16(f);   // RNE
    union { __hip_bfloat16 h; unsigned short u; } c; c.h = h;
    return c.u;
}

// ---------------------------------------------------------------------------
// Step 1: per-row histogram
// ---------------------------------------------------------------------------
__global__ __launch_bounds__(256) void hist_kernel(
    const int* __restrict__ row, int* __restrict__ cnt)
{
    int e = blockIdx.x * blockDim.x + threadIdx.x;
    if (e < NE) atomicAdd(&cnt[row[e]], 1);
}

// ---------------------------------------------------------------------------
// Step 2a: per-block sums (block = 1024 counts as 256 x int4)
// ---------------------------------------------------------------------------
__global__ __launch_bounds__(256) void scanA_kernel(
    const int* __restrict__ cnt, int* __restrict__ bsum)
{
    const int t = threadIdx.x, b = blockIdx.x;
    const int idx4 = b * 256 + t;
    int s = 0;
    if (idx4 < NN / 4) {
        int4 c = ((const int4*)cnt)[idx4];
        s = c.x + c.y + c.z + c.w;
    }
    for (int d = 32; d > 0; d >>= 1) s += __shfl_down(s, d);
    __shared__ int wsum[4];
    if ((t & 63) == 0) wsum[t >> 6] = s;
    __syncthreads();
    if (t == 0) bsum[b] = wsum[0] + wsum[1] + wsum[2] + wsum[3];
}

// ---------------------------------------------------------------------------
// Step 2b: exclusive scan of the 49 block sums (single wave)
// ---------------------------------------------------------------------------
__global__ __launch_bounds__(64) void scanB_kernel(int* __restrict__ bsum)
{
    const int t = threadIdx.x;
    int v = (t < SCAN_BLOCKS) ? bsum[t] : 0;
    int orig = v;
    for (int d = 1; d < 64; d <<= 1) {
        int u = __shfl_up(v, d);
        if (t >= d) v += u;
    }
    if (t < SCAN_BLOCKS) bsum[t] = v - orig;   // exclusive
}

// ---------------------------------------------------------------------------
// Step 2c: block-level exclusive scan + block offset -> off, cur
// ---------------------------------------------------------------------------
__global__ __launch_bounds__(256) void scanC_kernel(
    const int* __restrict__ cnt, const int* __restrict__ bsum,
    int* __restrict__ off, int* __restrict__ cur)
{
    const int t = threadIdx.x, b = blockIdx.x;
    const int idx4 = b * 256 + t;
    const bool valid = (idx4 < NN / 4);
    int4 c = make_int4(0, 0, 0, 0);
    if (valid) c = ((const int4*)cnt)[idx4];
    int s = c.x + c.y + c.z + c.w;

    const int lane = t & 63, w = t >> 6;
    int v = s;
    for (int d = 1; d < 64; d <<= 1) {
        int u = __shfl_up(v, d);
        if (lane >= d) v += u;
    }
    __shared__ int wsum[4];
    if (lane == 63) wsum[w] = v;
    __syncthreads();
    int woff = 0;
    for (int i = 0; i < 4; ++i) if (i < w) woff += wsum[i];

    if (valid) {
        int excl = (v - s) + woff + bsum[b];
        int4 o;
        o.x = excl;
        o.y = o.x + c.x;
        o.z = o.y + c.y;
        o.w = o.z + c.z;
        ((int4*)off)[idx4] = o;
        ((int4*)cur)[idx4] = o;
    }
}

// ---------------------------------------------------------------------------
// Step 3: bucket edges into CSR slots; store (e, col[e]).
// ---------------------------------------------------------------------------
__global__ __launch_bounds__(256) void bucket_kernel(
    const int* __restrict__ row, const int* __restrict__ col,
    int* __restrict__ cur, int2* __restrict__ perm)
{
    int e = blockIdx.x * blockDim.x + threadIdx.x;
    if (e >= NE) return;
    int pos = atomicAdd(&cur[row[e]], 1);
    perm[pos] = make_int2(e, col[e]);
}

// ---------------------------------------------------------------------------
// Step 4: gather-aggregate. One wave64 per node; edge loop unrolled x4.
// Writes A row as bf16: cols 0..95 = 0.5*sum(msg), cols 96..159 = x[node].
// ---------------------------------------------------------------------------
__global__ __launch_bounds__(256) void gather_kernel(
    const float* __restrict__ x,    // NN x 64
    const float* __restrict__ ea,   // NE x 16
    const float* __restrict__ et,   // NE x 16
    const int*  __restrict__ off,
    const int*  __restrict__ cnt,
    const int2* __restrict__ perm,
    unsigned short* __restrict__ A) // NN x 160 bf16
{
    const int node = blockIdx.x * 4 + (threadIdx.x >> 6);
    const int lane = threadIdx.x & 63;
    if (node >= NN) return;

    const int beg = off[node];
    const int n   = cnt[node];

    const float* eb = (lane < 16) ? (ea + lane) : (et + (lane - 16));

    float a0 = 0.f, a1 = 0.f, a2 = 0.f, a3 = 0.f;
    float b0 = 0.f, b1 = 0.f, b2 = 0.f, b3 = 0.f;
    int j = 0;
    for (; j + 4 <= n; j += 4) {
        int2 p0 = perm[beg + j];
        int2 p1 = perm[beg + j + 1];
        int2 p2 = perm[beg + j + 2];
        int2 p3 = perm[beg + j + 3];
        a0 += x[(size_t)p0.y * D_NODE + lane];
        a1 += x[(size_t)p1.y * D_NODE + lane];
        a2 += x[(size_t)p2.y * D_NODE + lane];
        a3 += x[(size_t)p3.y * D_NODE + lane];
        if (lane < 32) {
            b0 += eb[(size_t)p0.x * 16];
            b1 += eb[(size_t)p1.x * 16];
            b2 += eb[(size_t)p2.x * 16];
            b3 += eb[(size_t)p3.x * 16];
        }
    }
    for (; j < n; ++j) {
        int2 p = perm[beg + j];
        a0 += x[(size_t)p.y * D_NODE + lane];
        if (lane < 32) b0 += eb[(size_t)p.x * 16];
    }
    float accx = (a0 + a1) + (a2 + a3);
    float acce = (b0 + b1) + (b2 + b3);

    unsigned short* dst = A + (size_t)node * D_K;
    dst[lane] = f2bf(0.5f * accx);                             // cols 0..63
    if (lane < 32) dst[D_NODE + lane] = f2bf(0.5f * acce);     // cols 64..95
    dst[D_MSG + lane] = f2bf(x[(size_t)node * D_NODE + lane]); // cols 96..159
}

// ---------------------------------------------------------------------------
// Step 5: MFMA GEMM  out[50000,128] = A[50000,160] @ B[160,128] + bias
// ---------------------------------------------------------------------------
__global__ __launch_bounds__(256) void mfma_dense_kernel(
    const unsigned short* __restrict__ A,  // NN x 160 bf16
    const float* __restrict__ Wm,          // 96 x 128
    const float* __restrict__ bm,          // 128
    const float* __restrict__ Wr,          // 64 x 128
    const float* __restrict__ br,          // 128
    float*       __restrict__ out)         // NN x 128
{
    __shared__ unsigned short Bt[D_OUT * KP];   // 43008 B

    for (int i = threadIdx.x; i < D_K * D_OUT; i += 256) {
        int k = i >> 7, n = i & 127;
        float v = (k < D_MSG) ? Wm[i] : Wr[i - D_MSG * D_OUT];
        Bt[n * KP + k] = f2bf(v);
    }
    __syncthreads();

    const int l   = threadIdx.x & 63;
    const int wid = threadIdx.x >> 6;
    const int wm  = wid & 1;                   // M half (32 rows)
    const int wn  = wid >> 1;                  // N half (64 cols)
    const int lr  = l & 15;
    const int lk  = (l >> 4) << 3;             // k sub-offset 0/8/16/24

    bf16x8 bq[4][5];
#pragma unroll
    for (int nf = 0; nf < 4; ++nf) {
        int c = wn * 64 + nf * 16 + lr;
#pragma unroll
        for (int ks = 0; ks < 5; ++ks)
            bq[nf][ks] = *(const bf16x8*)(&Bt[c * KP + ks * 32 + lk]);
    }

    const int row0 = blockIdx.x * 64 + wm * 32;

    f32x4 acc[2][4];
#pragma unroll
    for (int mf = 0; mf < 2; ++mf)
#pragma unroll
        for (int nf = 0; nf < 4; ++nf)
            acc[mf][nf] = (f32x4){0.f, 0.f, 0.f, 0.f};

#pragma unroll
    for (int ks = 0; ks < 5; ++ks) {
#pragma unroll
        for (int mf = 0; mf < 2; ++mf) {
            int row = row0 + mf * 16 + lr;
            if (row > NN - 1) row = NN - 1;    // clamp (dup rows never stored)
            bf16x8 af = *(const bf16x8*)(A + (size_t)row * D_K + ks * 32 + lk);
#pragma unroll
            for (int nf = 0; nf < 4; ++nf)
                acc[mf][nf] = __builtin_amdgcn_mfma_f32_16x16x32_bf16(
                    af, bq[nf][ks], acc[mf][nf], 0, 0, 0);
        }
    }

#pragma unroll
    for (int nf = 0; nf < 4; ++nf) {
        int c = wn * 64 + nf * 16 + lr;
        float bias = 0.5f * bm[c] + br[c];
#pragma unroll
        for (int mf = 0; mf < 2; ++mf) {
            int rbase = row0 + mf * 16 + ((l >> 4) << 2);
#pragma unroll
            for (int r = 0; r < 4; ++r) {
                int row = rbase + r;
                if (row < NN) out[(size_t)row * D_OUT + c] = acc[mf][nf][r] + bias;
            }
        }
    }
}

extern "C" void kernel_launch(void* const* d_in, const int* in_sizes, int n_in,
                              void* d_out, int out_size, void* d_ws, size_t ws_size,
                              hipStream_t stream) {
    const float* x  = (const float*)d_in[0];
    const int*   ei = (const int*)d_in[1];   // row = ei[0:NE), col = ei[NE:2NE)
    const float* ea = (const float*)d_in[2];
    const float* et = (const float*)d_in[3];
    const float* Wm = (const float*)d_in[4];
    const float* bm = (const float*)d_in[5];
    const float* Wr = (const float*)d_in[6];
    const float* br = (const float*)d_in[7];
    float* out = (float*)d_out;
    const int* row = ei;
    const int* col = ei + NE;

    char* ws = (char*)d_ws;
    int*  cnt  = (int*)(ws + CNT_OFF);
    int*  off  = (int*)(ws + OFF_OFF);
    int*  cur  = (int*)(ws + CUR_OFF);
    int2* perm = (int2*)(ws + PERM_OFF);
    int*  bsum = (int*)(ws + BSUM_OFF);
    unsigned short* A = (unsigned short*)(ws + A_OFF);

    hipMemsetAsync(cnt, 0, NN * sizeof(int), stream);
    hist_kernel  <<<(NE + 255) / 256, 256, 0, stream>>>(row, cnt);
    scanA_kernel <<<SCAN_BLOCKS, 256, 0, stream>>>(cnt, bsum);
    scanB_kernel <<<1, 64, 0, stream>>>(bsum);
    scanC_kernel <<<SCAN_BLOCKS, 256, 0, stream>>>(cnt, bsum, off, cur);
    bucket_kernel<<<(NE + 255) / 256, 256, 0, stream>>>(row, col, cur, perm);
    gather_kernel<<<(NN + 3) / 4, 256, 0, stream>>>(x, ea, et, off, cnt, perm, A);
    mfma_dense_kernel<<<(NN + 63) / 64, 256, 0, stream>>>(A, Wm, bm, Wr, br, out);
}

// Round 7
// 178.988 us; speedup vs baseline: 2.3715x; 1.0233x over previous
//
#include <hip/hip_runtime.h>
#include <hip/hip_bf16.h>

#define NN 50000
#define NE 800000
#define D_NODE 64
#define D_MSG 96      // 64 + 16 + 16
#define D_K 160       // 96 (0.5*agg) + 64 (x)
#define D_OUT 128
#define KP 168        // LDS-padded K stride for Bt

#define SCAN_BLOCKS 49   // ceil(12500 int4 groups / 256)

typedef __attribute__((ext_vector_type(8))) short bf16x8;
typedef __attribute__((ext_vector_type(4))) float f32x4;

// ---------------- ws layout (all ranges disjoint!) ----------------
// cnt : [0,        200000)
// off : [200000,   400000)
// cur : [400000,   600000)
// perm: [600000,   7000000)   NE * 8   (16B aligned: 600000 % 16 == 0)
// A   : [7000064,  23000064)  NN * 160 * 2
// bsum: [23000064, 23000260)  49 ints
#define CNT_OFF  0
#define OFF_OFF  200000
#define CUR_OFF  400000
#define PERM_OFF 600000
#define A_OFF    7000064
#define BSUM_OFF 23000064
#define WS_NEEDED (BSUM_OFF + SCAN_BLOCKS * 4)

__device__ __forceinline__ unsigned short f2bf(float f) {
    __hip_bfloat16 h = __float2bfloat16(f);   // RNE
    union { __hip_bfloat16 h; unsigned short u; } c; c.h = h;
    return c.u;
}
__device__ __forceinline__ float bf2f(unsigned int u) {
    union { unsigned int i; float f; } c; c.i = u << 16; return c.f;
}

// ---------------------------------------------------------------------------
// Step 0: cast x rows to bf16 into A cols 96..159 (read by gather AND GEMM)
// ---------------------------------------------------------------------------
__global__ __launch_bounds__(256) void xcast_kernel(
    const float* __restrict__ x, unsigned short* __restrict__ A)
{
    int t = blockIdx.x * 256 + threadIdx.x;       // over NN*16 float4 groups
    if (t >= NN * 16) return;
    int node = t >> 4, c4 = t & 15;
    float4 v = *(const float4*)(x + (size_t)node * D_NODE + c4 * 4);
    uint2 pk;
    pk.x = (unsigned)f2bf(v.x) | ((unsigned)f2bf(v.y) << 16);
    pk.y = (unsigned)f2bf(v.z) | ((unsigned)f2bf(v.w) << 16);
    *(uint2*)(A + (size_t)node * D_K + D_MSG + c4 * 4) = pk;
}

// ---------------------------------------------------------------------------
// Step 1: per-row histogram
// ---------------------------------------------------------------------------
__global__ __launch_bounds__(256) void hist_kernel(
    const int* __restrict__ row, int* __restrict__ cnt)
{
    int e = blockIdx.x * blockDim.x + threadIdx.x;
    if (e < NE) atomicAdd(&cnt[row[e]], 1);
}

// ---------------------------------------------------------------------------
// Step 2a: per-block sums (block = 1024 counts as 256 x int4)
// ---------------------------------------------------------------------------
__global__ __launch_bounds__(256) void scanA_kernel(
    const int* __restrict__ cnt, int* __restrict__ bsum)
{
    const int t = threadIdx.x, b = blockIdx.x;
    const int idx4 = b * 256 + t;
    int s = 0;
    if (idx4 < NN / 4) {
        int4 c = ((const int4*)cnt)[idx4];
        s = c.x + c.y + c.z + c.w;
    }
    for (int d = 32; d > 0; d >>= 1) s += __shfl_down(s, d);
    __shared__ int wsum[4];
    if ((t & 63) == 0) wsum[t >> 6] = s;
    __syncthreads();
    if (t == 0) bsum[b] = wsum[0] + wsum[1] + wsum[2] + wsum[3];
}

// ---------------------------------------------------------------------------
// Step 2b: exclusive scan of the 49 block sums (single wave)
// ---------------------------------------------------------------------------
__global__ __launch_bounds__(64) void scanB_kernel(int* __restrict__ bsum)
{
    const int t = threadIdx.x;
    int v = (t < SCAN_BLOCKS) ? bsum[t] : 0;
    int orig = v;
    for (int d = 1; d < 64; d <<= 1) {
        int u = __shfl_up(v, d);
        if (t >= d) v += u;
    }
    if (t < SCAN_BLOCKS) bsum[t] = v - orig;   // exclusive
}

// ---------------------------------------------------------------------------
// Step 2c: block-level exclusive scan + block offset -> off, cur
// ---------------------------------------------------------------------------
__global__ __launch_bounds__(256) void scanC_kernel(
    const int* __restrict__ cnt, const int* __restrict__ bsum,
    int* __restrict__ off, int* __restrict__ cur)
{
    const int t = threadIdx.x, b = blockIdx.x;
    const int idx4 = b * 256 + t;
    const bool valid = (idx4 < NN / 4);
    int4 c = make_int4(0, 0, 0, 0);
    if (valid) c = ((const int4*)cnt)[idx4];
    int s = c.x + c.y + c.z + c.w;

    const int lane = t & 63, w = t >> 6;
    int v = s;
    for (int d = 1; d < 64; d <<= 1) {
        int u = __shfl_up(v, d);
        if (lane >= d) v += u;
    }
    __shared__ int wsum[4];
    if (lane == 63) wsum[w] = v;
    __syncthreads();
    int woff = 0;
    for (int i = 0; i < 4; ++i) if (i < w) woff += wsum[i];

    if (valid) {
        int excl = (v - s) + woff + bsum[b];
        int4 o;
        o.x = excl;
        o.y = o.x + c.x;
        o.z = o.y + c.y;
        o.w = o.z + c.z;
        ((int4*)off)[idx4] = o;
        ((int4*)cur)[idx4] = o;
    }
}

// ---------------------------------------------------------------------------
// Step 3: bucket edges into CSR slots; store (e, col[e]).
// ---------------------------------------------------------------------------
__global__ __launch_bounds__(256) void bucket_kernel(
    const int* __restrict__ row, const int* __restrict__ col,
    int* __restrict__ cur, int2* __restrict__ perm)
{
    int e = blockIdx.x * blockDim.x + threadIdx.x;
    if (e >= NE) return;
    int pos = atomicAdd(&cur[row[e]], 1);
    perm[pos] = make_int2(e, col[e]);
}

// ---------------------------------------------------------------------------
// Step 4: gather-aggregate, 2 edges per wave-pass.
//   lanes 0-31 : edge j   ; lanes 32-63 : edge j+1  (parity halves)
//   x part : lane reads ushort2 (2 bf16 cols) from A[col][96+2*hl .. ]
//   ea/et  : quarter-wave split (ea[j] | et[j] | ea[j+1] | et[j+1]), 1 instr
//   perm   : int4 = 2 edges per load (odd-beg peeled for 16B alignment)
// Final: __shfl_xor(32) parity combine; lanes 0-31 write cols 0..63 (uint),
// lanes 32-63 write cols 64..95 (ushort).
// ---------------------------------------------------------------------------
__global__ __launch_bounds__(256) void gather_kernel(
    const float* __restrict__ ea,   // NE x 16
    const float* __restrict__ et,   // NE x 16
    const int*  __restrict__ off,
    const int*  __restrict__ cnt,
    const int2* __restrict__ perm,
    unsigned short* __restrict__ A) // NN x 160 bf16
{
    const int node = blockIdx.x * 4 + (threadIdx.x >> 6);
    const int lane = threadIdx.x & 63;
    if (node >= NN) return;

    const int beg = off[node];
    const int end = beg + cnt[node];

    const int half = lane >> 5;          // 0: even edge of pair, 1: odd
    const int hl   = lane & 31;
    const float* ebase = ((lane >> 4) & 1) ? et : ea;
    const int ecol = lane & 15;

    float accx0 = 0.f, accx1 = 0.f;      // 2 x-cols per lane
    float acce  = 0.f;                   // 1 attr col per lane

    int j = beg;
    if ((j & 1) && j < end) {            // peel to even index
        int2 p = perm[j];
        if (half == 0) {
            unsigned xv = *(const unsigned*)(A + (size_t)p.y * D_K + D_MSG + hl * 2);
            accx0 += bf2f(xv & 0xffffu);
            accx1 += bf2f(xv >> 16);
            acce  += ebase[(size_t)p.x * 16 + ecol];
        }
        ++j;
    }
    for (; j + 4 <= end; j += 4) {       // 2 pairs per iter
        int4 q0 = *(const int4*)(perm + j);       // e0,c0,e1,c1
        int4 q1 = *(const int4*)(perm + j + 2);   // e2,c2,e3,c3
        int c01 = half ? q0.w : q0.y;
        int e01 = half ? q0.z : q0.x;
        int c23 = half ? q1.w : q1.y;
        int e23 = half ? q1.z : q1.x;
        unsigned xv0 = *(const unsigned*)(A + (size_t)c01 * D_K + D_MSG + hl * 2);
        unsigned xv1 = *(const unsigned*)(A + (size_t)c23 * D_K + D_MSG + hl * 2);
        float ev0 = ebase[(size_t)e01 * 16 + ecol];
        float ev1 = ebase[(size_t)e23 * 16 + ecol];
        accx0 += bf2f(xv0 & 0xffffu) + bf2f(xv1 & 0xffffu);
        accx1 += bf2f(xv0 >> 16)     + bf2f(xv1 >> 16);
        acce  += ev0 + ev1;
    }
    if (j + 2 <= end) {                  // last full pair
        int4 q0 = *(const int4*)(perm + j);
        int c01 = half ? q0.w : q0.y;
        int e01 = half ? q0.z : q0.x;
        unsigned xv0 = *(const unsigned*)(A + (size_t)c01 * D_K + D_MSG + hl * 2);
        accx0 += bf2f(xv0 & 0xffffu);
        accx1 += bf2f(xv0 >> 16);
        acce  += ebase[(size_t)e01 * 16 + ecol];
        j += 2;
    }
    if (j < end) {                       // final single edge
        int2 p = perm[j];
        if (half == 0) {
            unsigned xv = *(const unsigned*)(A + (size_t)p.y * D_K + D_MSG + hl * 2);
            accx0 += bf2f(xv & 0xffffu);
            accx1 += bf2f(xv >> 16);
            acce  += ebase[(size_t)p.x * 16 + ecol];
        }
    }

    // parity-half combine (lane l <-> l^32 hold same columns)
    accx0 += __shfl_xor(accx0, 32);
    accx1 += __shfl_xor(accx1, 32);
    acce  += __shfl_xor(acce, 32);

    unsigned short* dst = A + (size_t)node * D_K;
    if (half == 0) {
        unsigned pk = (unsigned)f2bf(0.5f * accx0)
                    | ((unsigned)f2bf(0.5f * accx1) << 16);
        *(unsigned*)(dst + hl * 2) = pk;           // cols 0..63
    } else {
        dst[D_NODE + hl] = f2bf(0.5f * acce);      // cols 64..95
    }
}

// ---------------------------------------------------------------------------
// Step 5: MFMA GEMM  out[50000,128] = A[50000,160] @ B[160,128] + bias
// ---------------------------------------------------------------------------
__global__ __launch_bounds__(256) void mfma_dense_kernel(
    const unsigned short* __restrict__ A,  // NN x 160 bf16
    const float* __restrict__ Wm,          // 96 x 128
    const float* __restrict__ bm,          // 128
    const float* __restrict__ Wr,          // 64 x 128
    const float* __restrict__ br,          // 128
    float*       __restrict__ out)         // NN x 128
{
    __shared__ unsigned short Bt[D_OUT * KP];   // 43008 B

    for (int i = threadIdx.x; i < D_K * D_OUT; i += 256) {
        int k = i >> 7, n = i & 127;
        float v = (k < D_MSG) ? Wm[i] : Wr[i - D_MSG * D_OUT];
        Bt[n * KP + k] = f2bf(v);
    }
    __syncthreads();

    const int l   = threadIdx.x & 63;
    const int wid = threadIdx.x >> 6;
    const int wm  = wid & 1;                   // M half (32 rows)
    const int wn  = wid >> 1;                  // N half (64 cols)
    const int lr  = l & 15;
    const int lk  = (l >> 4) << 3;             // k sub-offset 0/8/16/24

    bf16x8 bq[4][5];
#pragma unroll
    for (int nf = 0; nf < 4; ++nf) {
        int c = wn * 64 + nf * 16 + lr;
#pragma unroll
        for (int ks = 0; ks < 5; ++ks)
            bq[nf][ks] = *(const bf16x8*)(&Bt[c * KP + ks * 32 + lk]);
    }

    const int row0 = blockIdx.x * 64 + wm * 32;

    f32x4 acc[2][4];
#pragma unroll
    for (int mf = 0; mf < 2; ++mf)
#pragma unroll
        for (int nf = 0; nf < 4; ++nf)
            acc[mf][nf] = (f32x4){0.f, 0.f, 0.f, 0.f};

#pragma unroll
    for (int ks = 0; ks < 5; ++ks) {
#pragma unroll
        for (int mf = 0; mf < 2; ++mf) {
            int row = row0 + mf * 16 + lr;
            if (row > NN - 1) row = NN - 1;    // clamp (dup rows never stored)
            bf16x8 af = *(const bf16x8*)(A + (size_t)row * D_K + ks * 32 + lk);
#pragma unroll
            for (int nf = 0; nf < 4; ++nf)
                acc[mf][nf] = __builtin_amdgcn_mfma_f32_16x16x32_bf16(
                    af, bq[nf][ks], acc[mf][nf], 0, 0, 0);
        }
    }

#pragma unroll
    for (int nf = 0; nf < 4; ++nf) {
        int c = wn * 64 + nf * 16 + lr;
        float bias = 0.5f * bm[c] + br[c];
#pragma unroll
        for (int mf = 0; mf < 2; ++mf) {
            int rbase = row0 + mf * 16 + ((l >> 4) << 2);
#pragma unroll
            for (int r = 0; r < 4; ++r) {
                int row = rbase + r;
                if (row < NN) out[(size_t)row * D_OUT + c] = acc[mf][nf][r] + bias;
            }
        }
    }
}

extern "C" void kernel_launch(void* const* d_in, const int* in_sizes, int n_in,
                              void* d_out, int out_size, void* d_ws, size_t ws_size,
                              hipStream_t stream) {
    const float* x  = (const float*)d_in[0];
    const int*   ei = (const int*)d_in[1];   // row = ei[0:NE), col = ei[NE:2NE)
    const float* ea = (const float*)d_in[2];
    const float* et = (const float*)d_in[3];
    const float* Wm = (const float*)d_in[4];
    const float* bm = (const float*)d_in[5];
    const float* Wr = (const float*)d_in[6];
    const float* br = (const float*)d_in[7];
    float* out = (float*)d_out;
    const int* row = ei;
    const int* col = ei + NE;

    char* ws = (char*)d_ws;
    int*  cnt  = (int*)(ws + CNT_OFF);
    int*  off  = (int*)(ws + OFF_OFF);
    int*  cur  = (int*)(ws + CUR_OFF);
    int2* perm = (int2*)(ws + PERM_OFF);
    int*  bsum = (int*)(ws + BSUM_OFF);
    unsigned short* A = (unsigned short*)(ws + A_OFF);

    hipMemsetAsync(cnt, 0, NN * sizeof(int), stream);
    xcast_kernel <<<(NN * 16 + 255) / 256, 256, 0, stream>>>(x, A);
    hist_kernel  <<<(NE + 255) / 256, 256, 0, stream>>>(row, cnt);
    scanA_kernel <<<SCAN_BLOCKS, 256, 0, stream>>>(cnt, bsum);
    scanB_kernel <<<1, 64, 0, stream>>>(bsum);
    scanC_kernel <<<SCAN_BLOCKS, 256, 0, stream>>>(cnt, bsum, off, cur);
    bucket_kernel<<<(NE + 255) / 256, 256, 0, stream>>>(row, col, cur, perm);
    gather_kernel<<<(NN + 3) / 4, 256, 0, stream>>>(ea, et, off, cnt, perm, A);
    mfma_dense_kernel<<<(NN + 63) / 64, 256, 0, stream>>>(A, Wm, bm, Wr, br, out);
}

// Round 8
// 167.152 us; speedup vs baseline: 2.5395x; 1.0708x over previous
//
#include <hip/hip_runtime.h>
#include <hip/hip_bf16.h>

#define NN 50000
#define NE 800000
#define D_NODE 64
#define D_MSG 96      // 64 + 16 + 16
#define D_K 160       // compute K: 64 (x) + 96 (0.5*agg)
#define AS 192        // A row stride in bf16 (384 B, 128B-aligned rows)
#define D_OUT 128
#define KP 168        // LDS-padded K stride for Bt

#define SCAN_BLOCKS 49   // ceil(12500 int4 groups / 256)
#define XCAST_BLOCKS 3125  // NN*16/256

typedef __attribute__((ext_vector_type(8))) short bf16x8;
typedef __attribute__((ext_vector_type(4))) float f32x4;

// ---------------- ws layout (all ranges disjoint / ordering-safe) ----------
// cnt : [0,        200000)
// off : [200000,   400000)
// cur : [400000,   600000)
// perm: [600000,   7000000)   NE * 8  (16B aligned)
// A   : [7000064,  26200064)  NN * 192 * 2   (row bases 128B-aligned)
//   A layout per row: [x bf16 (cols 0-63) | 0.5*msg_x (64-127) |
//                      0.5*msg_e (128-159) | pad (160-191, never read)]
// bsum: A_OFF+128 .. +324 — lives in A row 0 cols 64..161. Safe: xcast writes
//   row0 cols 0-63 only; scanA writes bsum AFTER xcast, scanC reads it BEFORE
//   bucket/gather; gather later overwrites cols 64-159 with real agg values.
#define CNT_OFF  0
#define OFF_OFF  200000
#define CUR_OFF  400000
#define PERM_OFF 600000
#define A_OFF    7000064
#define BSUM_OFF (A_OFF + 128)

__device__ __forceinline__ unsigned short f2bf(float f) {
    __hip_bfloat16 h = __float2bfloat16(f);   // RNE
    union { __hip_bfloat16 h; unsigned short u; } c; c.h = h;
    return c.u;
}
__device__ __forceinline__ float bf2f(unsigned int u) {
    union { unsigned int i; float f; } c; c.i = u << 16; return c.f;
}

// ---------------------------------------------------------------------------
// Step 1 (fused): blocks [0,3125): cast x -> A cols 0..63 (bf16, aligned);
//                 blocks [3125,6250): per-row histogram.
// ---------------------------------------------------------------------------
__global__ __launch_bounds__(256) void prep_kernel(
    const float* __restrict__ x, unsigned short* __restrict__ A,
    const int* __restrict__ row, int* __restrict__ cnt)
{
    const int b = blockIdx.x;
    if (b < XCAST_BLOCKS) {
        int t = b * 256 + threadIdx.x;        // < NN*16 exactly
        int node = t >> 4, c4 = t & 15;
        float4 v = *(const float4*)(x + (size_t)node * D_NODE + c4 * 4);
        uint2 pk;
        pk.x = (unsigned)f2bf(v.x) | ((unsigned)f2bf(v.y) << 16);
        pk.y = (unsigned)f2bf(v.z) | ((unsigned)f2bf(v.w) << 16);
        *(uint2*)(A + (size_t)node * AS + c4 * 4) = pk;
    } else {
        int e = (b - XCAST_BLOCKS) * 256 + threadIdx.x;
        if (e < NE) atomicAdd(&cnt[row[e]], 1);
    }
}

// ---------------------------------------------------------------------------
// Step 2a: per-block sums (block = 1024 counts as 256 x int4)
// ---------------------------------------------------------------------------
__global__ __launch_bounds__(256) void scanA_kernel(
    const int* __restrict__ cnt, int* __restrict__ bsum)
{
    const int t = threadIdx.x, b = blockIdx.x;
    const int idx4 = b * 256 + t;
    int s = 0;
    if (idx4 < NN / 4) {
        int4 c = ((const int4*)cnt)[idx4];
        s = c.x + c.y + c.z + c.w;
    }
    for (int d = 32; d > 0; d >>= 1) s += __shfl_down(s, d);
    __shared__ int wsum[4];
    if ((t & 63) == 0) wsum[t >> 6] = s;
    __syncthreads();
    if (t == 0) bsum[b] = wsum[0] + wsum[1] + wsum[2] + wsum[3];
}

// ---------------------------------------------------------------------------
// Step 2b: block exclusive scan + inline top-level scan of the 49 bsums
// ---------------------------------------------------------------------------
__global__ __launch_bounds__(256) void scanC_kernel(
    const int* __restrict__ cnt, const int* __restrict__ bsum,
    int* __restrict__ off, int* __restrict__ cur)
{
    __shared__ int s_boff;
    __shared__ int wsum[4];
    const int t = threadIdx.x, b = blockIdx.x;

    if (t < 64) {                       // wave 0: scan the 49 block sums
        int v = (t < SCAN_BLOCKS) ? bsum[t] : 0;
        int orig = v;
        for (int d = 1; d < 64; d <<= 1) {
            int u = __shfl_up(v, d);
            if (t >= d) v += u;
        }
        int excl = v - orig;
        int want = __shfl(excl, b);     // this block's global offset
        if (t == 0) s_boff = want;
    }

    const int idx4 = b * 256 + t;
    const bool valid = (idx4 < NN / 4);
    int4 c = make_int4(0, 0, 0, 0);
    if (valid) c = ((const int4*)cnt)[idx4];
    int s = c.x + c.y + c.z + c.w;

    const int lane = t & 63, w = t >> 6;
    int v = s;
    for (int d = 1; d < 64; d <<= 1) {
        int u = __shfl_up(v, d);
        if (lane >= d) v += u;
    }
    if (lane == 63) wsum[w] = v;
    __syncthreads();
    int woff = 0;
    for (int i = 0; i < 4; ++i) if (i < w) woff += wsum[i];

    if (valid) {
        int excl = (v - s) + woff + s_boff;
        int4 o;
        o.x = excl;
        o.y = o.x + c.x;
        o.z = o.y + c.y;
        o.w = o.z + c.z;
        ((int4*)off)[idx4] = o;
        ((int4*)cur)[idx4] = o;
    }
}

// ---------------------------------------------------------------------------
// Step 3: bucket edges into CSR slots; store (e, col[e]).
// ---------------------------------------------------------------------------
__global__ __launch_bounds__(256) void bucket_kernel(
    const int* __restrict__ row, const int* __restrict__ col,
    int* __restrict__ cur, int2* __restrict__ perm)
{
    int e = blockIdx.x * blockDim.x + threadIdx.x;
    if (e >= NE) return;
    int pos = atomicAdd(&cur[row[e]], 1);
    perm[pos] = make_int2(e, col[e]);
}

// ---------------------------------------------------------------------------
// Step 4: gather-aggregate, 2 edges per wave-pass, 8-edge main unroll.
//   lanes 0-31: even edge of pair, lanes 32-63: odd edge.
//   x: lane reads one aligned uint (2 bf16 cols) from A[col] cols 0..63 —
//      exactly ONE 128B line per edge (row bases 128B-aligned, AS=192).
//   ea/et: quarter-wave split, 4x64B per pair of edges.
//   perm: int4 = 2 edges/load.
// Writes A cols 64..127 (0.5*msg_x) and 128..159 (0.5*msg_e).
// ---------------------------------------------------------------------------
__global__ __launch_bounds__(256) void gather_kernel(
    const float* __restrict__ ea,   // NE x 16
    const float* __restrict__ et,   // NE x 16
    const int*  __restrict__ off,
    const int*  __restrict__ cnt,
    const int2* __restrict__ perm,
    unsigned short* __restrict__ A)
{
    const int node = blockIdx.x * 4 + (threadIdx.x >> 6);
    const int lane = threadIdx.x & 63;
    if (node >= NN) return;

    const int beg = off[node];
    const int end = beg + cnt[node];

    const int half = lane >> 5;          // 0: even edge, 1: odd edge
    const int hl   = lane & 31;
    const float* ebase = ((lane >> 4) & 1) ? et : ea;
    const int ecol = lane & 15;

    float accx0 = 0.f, accx1 = 0.f, acce = 0.f;
    float accx0b = 0.f, accx1b = 0.f, acceb = 0.f;

#define EDGE_PAIR(q, ax0, ax1, ae)                                          \
    {                                                                       \
        int cc = half ? (q).w : (q).y;                                      \
        int ee = half ? (q).z : (q).x;                                      \
        unsigned xv = *(const unsigned*)(A + (size_t)cc * AS + hl * 2);     \
        float ev = ebase[(size_t)ee * 16 + ecol];                           \
        ax0 += bf2f(xv & 0xffffu);                                          \
        ax1 += bf2f(xv >> 16);                                              \
        ae  += ev;                                                          \
    }

    int j = beg;
    if ((j & 1) && j < end) {            // peel to even index
        int2 p = perm[j];
        if (half == 0) {
            unsigned xv = *(const unsigned*)(A + (size_t)p.y * AS + hl * 2);
            accx0 += bf2f(xv & 0xffffu);
            accx1 += bf2f(xv >> 16);
            acce  += ebase[(size_t)p.x * 16 + ecol];
        }
        ++j;
    }
    for (; j + 8 <= end; j += 8) {       // 4 pairs per iter (12 loads in flight)
        int4 q0 = *(const int4*)(perm + j);
        int4 q1 = *(const int4*)(perm + j + 2);
        int4 q2 = *(const int4*)(perm + j + 4);
        int4 q3 = *(const int4*)(perm + j + 6);
        EDGE_PAIR(q0, accx0, accx1, acce)
        EDGE_PAIR(q1, accx0b, accx1b, acceb)
        EDGE_PAIR(q2, accx0, accx1, acce)
        EDGE_PAIR(q3, accx0b, accx1b, acceb)
    }
    if (j + 4 <= end) {                  // 2 pairs
        int4 q0 = *(const int4*)(perm + j);
        int4 q1 = *(const int4*)(perm + j + 2);
        EDGE_PAIR(q0, accx0, accx1, acce)
        EDGE_PAIR(q1, accx0b, accx1b, acceb)
        j += 4;
    }
    if (j + 2 <= end) {                  // 1 pair
        int4 q0 = *(const int4*)(perm + j);
        EDGE_PAIR(q0, accx0, accx1, acce)
        j += 2;
    }
    if (j < end) {                       // final single edge
        int2 p = perm[j];
        if (half == 0) {
            unsigned xv = *(const unsigned*)(A + (size_t)p.y * AS + hl * 2);
            accx0 += bf2f(xv & 0xffffu);
            accx1 += bf2f(xv >> 16);
            acce  += ebase[(size_t)p.x * 16 + ecol];
        }
    }
#undef EDGE_PAIR

    accx0 += accx0b; accx1 += accx1b; acce += acceb;
    accx0 += __shfl_xor(accx0, 32);
    accx1 += __shfl_xor(accx1, 32);
    acce  += __shfl_xor(acce, 32);

    unsigned short* dst = A + (size_t)node * AS;
    if (half == 0) {
        unsigned pk = (unsigned)f2bf(0.5f * accx0)
                    | ((unsigned)f2bf(0.5f * accx1) << 16);
        *(unsigned*)(dst + D_NODE + hl * 2) = pk;       // cols 64..127
    } else {
        dst[2 * D_NODE + hl] = f2bf(0.5f * acce);       // cols 128..159
    }
}

// ---------------------------------------------------------------------------
// Step 5: MFMA GEMM  out[50000,128] = A[:, 0:160] @ [Wr ; Wm] + bias
// (A cols 0-63 = x vs Wr; cols 64-159 = 0.5*agg vs Wm). bias = 0.5*bm+br.
// ---------------------------------------------------------------------------
__global__ __launch_bounds__(256) void mfma_dense_kernel(
    const unsigned short* __restrict__ A,  // NN x AS bf16
    const float* __restrict__ Wm,          // 96 x 128
    const float* __restrict__ bm,          // 128
    const float* __restrict__ Wr,          // 64 x 128
    const float* __restrict__ br,          // 128
    float*       __restrict__ out)         // NN x 128
{
    __shared__ unsigned short Bt[D_OUT * KP];   // 43008 B

    for (int i = threadIdx.x; i < D_K * D_OUT; i += 256) {
        int k = i >> 7, n = i & 127;
        float v = (k < D_NODE) ? Wr[i] : Wm[i - D_NODE * D_OUT];
        Bt[n * KP + k] = f2bf(v);
    }
    __syncthreads();

    const int l   = threadIdx.x & 63;
    const int wid = threadIdx.x >> 6;
    const int wm  = wid & 1;                   // M half (32 rows)
    const int wn  = wid >> 1;                  // N half (64 cols)
    const int lr  = l & 15;
    const int lk  = (l >> 4) << 3;             // k sub-offset 0/8/16/24

    bf16x8 bq[4][5];
#pragma unroll
    for (int nf = 0; nf < 4; ++nf) {
        int c = wn * 64 + nf * 16 + lr;
#pragma unroll
        for (int ks = 0; ks < 5; ++ks)
            bq[nf][ks] = *(const bf16x8*)(&Bt[c * KP + ks * 32 + lk]);
    }

    const int row0 = blockIdx.x * 64 + wm * 32;

    f32x4 acc[2][4];
#pragma unroll
    for (int mf = 0; mf < 2; ++mf)
#pragma unroll
        for (int nf = 0; nf < 4; ++nf)
            acc[mf][nf] = (f32x4){0.f, 0.f, 0.f, 0.f};

#pragma unroll
    for (int ks = 0; ks < 5; ++ks) {
#pragma unroll
        for (int mf = 0; mf < 2; ++mf) {
            int row = row0 + mf * 16 + lr;
            if (row > NN - 1) row = NN - 1;    // clamp (dup rows never stored)
            bf16x8 af = *(const bf16x8*)(A + (size_t)row * AS + ks * 32 + lk);
#pragma unroll
            for (int nf = 0; nf < 4; ++nf)
                acc[mf][nf] = __builtin_amdgcn_mfma_f32_16x16x32_bf16(
                    af, bq[nf][ks], acc[mf][nf], 0, 0, 0);
        }
    }

#pragma unroll
    for (int nf = 0; nf < 4; ++nf) {
        int c = wn * 64 + nf * 16 + lr;
        float bias = 0.5f * bm[c] + br[c];
#pragma unroll
        for (int mf = 0; mf < 2; ++mf) {
            int rbase = row0 + mf * 16 + ((l >> 4) << 2);
#pragma unroll
            for (int r = 0; r < 4; ++r) {
                int row = rbase + r;
                if (row < NN) out[(size_t)row * D_OUT + c] = acc[mf][nf][r] + bias;
            }
        }
    }
}

extern "C" void kernel_launch(void* const* d_in, const int* in_sizes, int n_in,
                              void* d_out, int out_size, void* d_ws, size_t ws_size,
                              hipStream_t stream) {
    const float* x  = (const float*)d_in[0];
    const int*   ei = (const int*)d_in[1];   // row = ei[0:NE), col = ei[NE:2NE)
    const float* ea = (const float*)d_in[2];
    const float* et = (const float*)d_in[3];
    const float* Wm = (const float*)d_in[4];
    const float* bm = (const float*)d_in[5];
    const float* Wr = (const float*)d_in[6];
    const float* br = (const float*)d_in[7];
    float* out = (float*)d_out;
    const int* row = ei;
    const int* col = ei + NE;

    char* ws = (char*)d_ws;
    int*  cnt  = (int*)(ws + CNT_OFF);
    int*  off  = (int*)(ws + OFF_OFF);
    int*  cur  = (int*)(ws + CUR_OFF);
    int2* perm = (int2*)(ws + PERM_OFF);
    int*  bsum = (int*)(ws + BSUM_OFF);      // inside A row 0 (see layout note)
    unsigned short* A = (unsigned short*)(ws + A_OFF);

    hipMemsetAsync(cnt, 0, NN * sizeof(int), stream);
    prep_kernel  <<<2 * XCAST_BLOCKS, 256, 0, stream>>>(x, A, row, cnt);
    scanA_kernel <<<SCAN_BLOCKS, 256, 0, stream>>>(cnt, bsum);
    scanC_kernel <<<SCAN_BLOCKS, 256, 0, stream>>>(cnt, bsum, off, cur);
    bucket_kernel<<<(NE + 255) / 256, 256, 0, stream>>>(row, col, cur, perm);
    gather_kernel<<<(NN + 3) / 4, 256, 0, stream>>>(ea, et, off, cnt, perm, A);
    mfma_dense_kernel<<<(NN + 63) / 64, 256, 0, stream>>>(A, Wm, bm, Wr, br, out);
}